// Round 1
// baseline (501.713 us; speedup 1.0000x reference)
//
#include <hip/hip_runtime.h>

#define N_NODES 50000
#define N_EDGES 600000
#define HIDW 128

// ---------------------------------------------------------------- CSR build

__global__ void count_kernel(const int* __restrict__ dst, int* __restrict__ cnt) {
    int e = blockIdx.x * blockDim.x + threadIdx.x;
    if (e < N_EDGES) atomicAdd(&cnt[dst[e]], 1);
}

// single-block Hillis-Steele scan over N_NODES counts -> rowptr[0..N]
__global__ void scan_kernel(const int* __restrict__ cnt, int* __restrict__ rowptr) {
    __shared__ int sm[1024];
    int tid = threadIdx.x;
    int carry = 0;
    if (tid == 0) rowptr[0] = 0;
    for (int base = 0; base < N_NODES; base += 1024) {
        int i = base + tid;
        int v = (i < N_NODES) ? cnt[i] : 0;
        sm[tid] = v;
        __syncthreads();
        for (int off = 1; off < 1024; off <<= 1) {
            int t = (tid >= off) ? sm[tid - off] : 0;
            __syncthreads();
            sm[tid] += t;
            __syncthreads();
        }
        int incl = sm[tid];
        int total = sm[1023];
        if (i < N_NODES) rowptr[i + 1] = incl + carry;
        carry += total;
        __syncthreads();   // before next chunk overwrites sm
    }
}

__global__ void fill_kernel(const int* __restrict__ src, const int* __restrict__ dst,
                            const int* __restrict__ rowptr, int* __restrict__ cursor,
                            int* __restrict__ col) {
    int e = blockIdx.x * blockDim.x + threadIdx.x;
    if (e < N_EDGES) {
        int d = dst[e];
        int pos = atomicAdd(&cursor[d], 1);
        col[rowptr[d] + pos] = src[e];
    }
}

__global__ void deginv_kernel(const int* __restrict__ cnt, float* __restrict__ deg_inv) {
    int i = blockIdx.x * blockDim.x + threadIdx.x;
    if (i < N_NODES) deg_inv[i] = 1.0f / (float)max(cnt[i], 1);
}

// ---------------------------------------------------------------- aggregate
// one block per node, thread = feature channel; registers accumulate, no atomics
__global__ void aggregate_kernel(const float* __restrict__ h, const int* __restrict__ rowptr,
                                 const int* __restrict__ col, const float* __restrict__ deg_inv,
                                 float* __restrict__ agg) {
    int node = blockIdx.x;
    int t = threadIdx.x;                       // blockDim = 128
    int beg = rowptr[node], end = rowptr[node + 1];
    float s = 0.f;
    for (int e = beg; e < end; ++e) {
        int sn = col[e];
        s += h[(size_t)sn * HIDW + t];
    }
    agg[(size_t)node * HIDW + t] = s * deg_inv[node];
}

// ---------------------------------------------------------------- combine GEMM
// out[n, j] = relu( h[n,:] @ Wself + agg[n,:] @ Wneigh + b )  as one K=256 GEMM
// 64x64 tile, 256 threads, 4x4 register blocking, f32 vector ALU
template <int NOUT, bool RELU>
__global__ __launch_bounds__(256) void combine_gemm(
    const float* __restrict__ h, const float* __restrict__ agg,
    const float* __restrict__ Wself, const float* __restrict__ Wneigh,
    const float* __restrict__ bias, float* __restrict__ out)
{
    __shared__ float As[16][68];   // [k][m], padded
    __shared__ float Bs[16][64];   // [k][j]

    const int tid = threadIdx.x;
    const int bm = blockIdx.x;
    const int bn = blockIdx.y;
    const int tx = tid & 15;       // M direction
    const int ty = tid >> 4;       // N direction
    const int row0 = bm * 64;

    // A staging: thread -> (row, 4 consecutive k)
    const int ar = tid >> 2;            // 0..63
    const int ak = (tid & 3) << 2;      // 0,4,8,12
    // B staging: thread -> (k, 4 consecutive j)
    const int bk = tid >> 4;            // 0..15
    const int bj = (tid & 15) << 2;     // 0..60

    float acc[4][4] = {};

    for (int k0 = 0; k0 < 256; k0 += 16) {
        // stage A (h for k<128, agg for k>=128)
        int grow = row0 + ar;
        int kg = k0 + ak;
        float4 av = make_float4(0.f, 0.f, 0.f, 0.f);
        if (grow < N_NODES) {
            const float* sp = (kg < 128) ? &h[(size_t)grow * 128 + kg]
                                         : &agg[(size_t)grow * 128 + (kg - 128)];
            av = *(const float4*)sp;
        }
        As[ak + 0][ar] = av.x;
        As[ak + 1][ar] = av.y;
        As[ak + 2][ar] = av.z;
        As[ak + 3][ar] = av.w;
        // stage B (Wself for k<128, Wneigh for k>=128)
        int kgb = k0 + bk;
        const float* wp = (kgb < 128) ? &Wself[(size_t)kgb * NOUT + bn * 64 + bj]
                                      : &Wneigh[(size_t)(kgb - 128) * NOUT + bn * 64 + bj];
        *(float4*)&Bs[bk][bj] = *(const float4*)wp;
        __syncthreads();

        #pragma unroll
        for (int k = 0; k < 16; ++k) {
            float4 a = *(const float4*)&As[k][tx * 4];
            float4 b = *(const float4*)&Bs[k][ty * 4];
            float am[4] = {a.x, a.y, a.z, a.w};
            float bv[4] = {b.x, b.y, b.z, b.w};
            #pragma unroll
            for (int i = 0; i < 4; ++i)
                #pragma unroll
                for (int j = 0; j < 4; ++j)
                    acc[i][j] += am[i] * bv[j];
        }
        __syncthreads();
    }

    // epilogue: bias (+relu), float4 stores
    #pragma unroll
    for (int i = 0; i < 4; ++i) {
        int grow = row0 + tx * 4 + i;
        if (grow < N_NODES) {
            int gcol = bn * 64 + ty * 4;
            float4 o;
            float v0 = acc[i][0] + bias[gcol + 0];
            float v1 = acc[i][1] + bias[gcol + 1];
            float v2 = acc[i][2] + bias[gcol + 2];
            float v3 = acc[i][3] + bias[gcol + 3];
            if (RELU) {
                v0 = fmaxf(v0, 0.f); v1 = fmaxf(v1, 0.f);
                v2 = fmaxf(v2, 0.f); v3 = fmaxf(v3, 0.f);
            }
            o.x = v0; o.y = v1; o.z = v2; o.w = v3;
            *(float4*)&out[(size_t)grow * NOUT + gcol] = o;
        }
    }
}

// ---------------------------------------------------------------- launch

extern "C" void kernel_launch(void* const* d_in, const int* in_sizes, int n_in,
                              void* d_out, int out_size, void* d_ws, size_t ws_size,
                              hipStream_t stream) {
    const float* x   = (const float*)d_in[0];
    const int*   src = (const int*)d_in[1];
    const int*   dst = (const int*)d_in[2];
    const float* Ws0 = (const float*)d_in[3];
    const float* Wn0 = (const float*)d_in[4];
    const float* b0  = (const float*)d_in[5];
    const float* Ws1 = (const float*)d_in[6];
    const float* Wn1 = (const float*)d_in[7];
    const float* b1  = (const float*)d_in[8];
    const float* Ws2 = (const float*)d_in[9];
    const float* Wn2 = (const float*)d_in[10];
    const float* b2  = (const float*)d_in[11];
    float* out = (float*)d_out;

    char* p = (char*)d_ws;
    auto alloc = [&](size_t bytes) {
        char* r = p;
        p += (bytes + 255) & ~(size_t)255;
        return r;
    };
    int*   cnt    = (int*)alloc((size_t)N_NODES * 4);
    int*   cursor = (int*)alloc((size_t)N_NODES * 4);
    int*   rowptr = (int*)alloc((size_t)(N_NODES + 1) * 4);
    int*   col    = (int*)alloc((size_t)N_EDGES * 4);
    float* deginv = (float*)alloc((size_t)N_NODES * 4);
    float* agg    = (float*)alloc((size_t)N_NODES * HIDW * 4);
    float* hA     = (float*)alloc((size_t)N_NODES * HIDW * 4);
    float* hB     = (float*)alloc((size_t)N_NODES * HIDW * 4);

    hipMemsetAsync(cnt, 0, (size_t)N_NODES * 4, stream);
    hipMemsetAsync(cursor, 0, (size_t)N_NODES * 4, stream);

    count_kernel<<<(N_EDGES + 255) / 256, 256, 0, stream>>>(dst, cnt);
    scan_kernel<<<1, 1024, 0, stream>>>(cnt, rowptr);
    fill_kernel<<<(N_EDGES + 255) / 256, 256, 0, stream>>>(src, dst, rowptr, cursor, col);
    deginv_kernel<<<(N_NODES + 255) / 256, 256, 0, stream>>>(cnt, deginv);

    const int MB = (N_NODES + 63) / 64;   // 782
    dim3 g01(MB, 2), g2(MB, 1);

    // layer 0
    aggregate_kernel<<<N_NODES, 128, 0, stream>>>(x, rowptr, col, deginv, agg);
    combine_gemm<128, true><<<g01, 256, 0, stream>>>(x, agg, Ws0, Wn0, b0, hA);
    // layer 1
    aggregate_kernel<<<N_NODES, 128, 0, stream>>>(hA, rowptr, col, deginv, agg);
    combine_gemm<128, true><<<g01, 256, 0, stream>>>(hA, agg, Ws1, Wn1, b1, hB);
    // layer 2
    aggregate_kernel<<<N_NODES, 128, 0, stream>>>(hB, rowptr, col, deginv, agg);
    combine_gemm<64, false><<<g2, 256, 0, stream>>>(hB, agg, Ws2, Wn2, b2, out);
}

// Round 2
// 375.738 us; speedup vs baseline: 1.3353x; 1.3353x over previous
//
#include <hip/hip_runtime.h>

#define N_NODES 50000
#define N_EDGES 600000
#define HIDW 128
#define NPART 196   // ceil(50000/256)

using f32x4  = __attribute__((ext_vector_type(4))) float;
using bf16x8 = __attribute__((ext_vector_type(8))) short;

__device__ inline short f2bf(float f) {
    uint32_t u = __builtin_bit_cast(uint32_t, f);
    uint32_t r = (u + 0x7FFFu + ((u >> 16) & 1u)) >> 16;
    return (short)r;
}
__device__ inline float bf2f(short h) {
    uint32_t u = ((uint32_t)(uint16_t)h) << 16;
    return __builtin_bit_cast(float, u);
}

// ---------------------------------------------------------------- CSR build

__global__ void count_kernel(const int* __restrict__ dst, int* __restrict__ cnt) {
    int e = blockIdx.x * blockDim.x + threadIdx.x;
    if (e < N_EDGES) atomicAdd(&cnt[dst[e]], 1);
}

__global__ void scan_part(const int* __restrict__ cnt, int* __restrict__ partials) {
    __shared__ int sm[256];
    int b = blockIdx.x, t = threadIdx.x;
    int i = b * 256 + t;
    sm[t] = (i < N_NODES) ? cnt[i] : 0;
    __syncthreads();
    for (int off = 128; off > 0; off >>= 1) {
        if (t < off) sm[t] += sm[t + off];
        __syncthreads();
    }
    if (t == 0) partials[b] = sm[0];
}

__global__ void scan_mid(const int* __restrict__ partials, int* __restrict__ offsets) {
    __shared__ int sm[256];
    int t = threadIdx.x;
    int v = (t < NPART) ? partials[t] : 0;
    sm[t] = v;
    __syncthreads();
    for (int off = 1; off < 256; off <<= 1) {
        int u = (t >= off) ? sm[t - off] : 0;
        __syncthreads();
        sm[t] += u;
        __syncthreads();
    }
    if (t < NPART) offsets[t] = sm[t] - v;   // exclusive prefix
}

__global__ void scan_final(const int* __restrict__ cnt, const int* __restrict__ offsets,
                           int* __restrict__ rowptr) {
    __shared__ int sm[256];
    int b = blockIdx.x, t = threadIdx.x;
    int i = b * 256 + t;
    int v = (i < N_NODES) ? cnt[i] : 0;
    sm[t] = v;
    __syncthreads();
    for (int off = 1; off < 256; off <<= 1) {
        int u = (t >= off) ? sm[t - off] : 0;
        __syncthreads();
        sm[t] += u;
        __syncthreads();
    }
    if (i < N_NODES) rowptr[i + 1] = sm[t] + offsets[b];
    if (i == 0) rowptr[0] = 0;
}

__global__ void fill_kernel(const int* __restrict__ src, const int* __restrict__ dst,
                            const int* __restrict__ rowptr, int* __restrict__ cursor,
                            int* __restrict__ col) {
    int e = blockIdx.x * blockDim.x + threadIdx.x;
    if (e < N_EDGES) {
        int d = dst[e];
        int pos = atomicAdd(&cursor[d], 1);
        col[rowptr[d] + pos] = src[e];
    }
}

__global__ void deginv_kernel(const int* __restrict__ cnt, float* __restrict__ deg_inv) {
    int i = blockIdx.x * blockDim.x + threadIdx.x;
    if (i < N_NODES) deg_inv[i] = 1.0f / (float)max(cnt[i], 1);
}

// ---------------------------------------------------------------- aggregate (f32)

__global__ void aggregate_kernel(const float* __restrict__ h, const int* __restrict__ rowptr,
                                 const int* __restrict__ col, const float* __restrict__ deg_inv,
                                 float* __restrict__ agg) {
    int node = blockIdx.x;
    int t = threadIdx.x;                       // blockDim = 128
    int beg = rowptr[node], end = rowptr[node + 1];
    float s = 0.f;
    int e = beg;
    for (; e + 1 < end; e += 2) {
        int s0 = col[e], s1 = col[e + 1];
        float v0 = h[(size_t)s0 * HIDW + t];
        float v1 = h[(size_t)s1 * HIDW + t];
        s += v0 + v1;
    }
    if (e < end) s += h[(size_t)col[e] * HIDW + t];
    agg[(size_t)node * HIDW + t] = s * deg_inv[node];
}

// ---------------------------------------------------------------- weight prep
// Wt_hi/Wt_lo: [NOUT][256] bf16 (transposed + split); k<128 -> Wself, k>=128 -> Wneigh

template <int NOUT>
__global__ void wsplit_kernel(const float* __restrict__ Ws, const float* __restrict__ Wn,
                              short* __restrict__ Wt_hi, short* __restrict__ Wt_lo) {
    int idx = blockIdx.x * 256 + threadIdx.x;      // c*256 + k
    if (idx >= NOUT * 256) return;
    int c = idx >> 8, k = idx & 255;
    float v = (k < 128) ? Ws[(size_t)k * NOUT + c] : Wn[(size_t)(k - 128) * NOUT + c];
    short hi = f2bf(v);
    float lo = v - bf2f(hi);
    Wt_hi[idx] = hi;
    Wt_lo[idx] = f2bf(lo);
}

// ---------------------------------------------------------------- combine GEMM (MFMA, split bf16)
// out[n,j] = relu( [h|agg][n,:] @ Wcat[:,j] + b ), K=256, f32-accurate via hi/lo split.
// Block: 256 thr (4 waves), tile 128x64. A staged f32->bf16(hi,lo) in swizzled LDS.
// B read directly from global (weights L1/L2-hot).

template <int NOUT, bool RELU>
__global__ __launch_bounds__(256) void combine_mfma(
    const float* __restrict__ h, const float* __restrict__ agg,
    const short* __restrict__ Wt_hi, const short* __restrict__ Wt_lo,
    const float* __restrict__ bias, float* __restrict__ out)
{
    __shared__ __attribute__((aligned(16))) short Ahi[128 * 64];
    __shared__ __attribute__((aligned(16))) short Alo[128 * 64];

    const int tid  = threadIdx.x;
    const int lane = tid & 63;
    const int wave = tid >> 6;
    const int bm = blockIdx.x, bn = blockIdx.y;
    const int row0 = bm * 128;

    f32x4 acc[2][4];
    #pragma unroll
    for (int i = 0; i < 2; ++i)
        #pragma unroll
        for (int j = 0; j < 4; ++j)
            acc[i][j] = (f32x4){0.f, 0.f, 0.f, 0.f};

    const int rr = lane & 15;
    const int kg = lane >> 4;

    for (int kt = 0; kt < 4; ++kt) {
        const float* srcbase = (kt < 2) ? h : agg;
        const int kbase = (kt & 1) * 64;

        // ---- stage A tile: 128 rows x 64 k (f32) -> split bf16 hi/lo, XOR-swizzled
        #pragma unroll
        for (int it = 0; it < 4; ++it) {
            int cid = it * 256 + tid;        // 0..1023 chunks of 8 f32
            int r   = cid >> 3;              // 0..127
            int c8  = cid & 7;               // 0..7
            int grow = row0 + r;
            float4 v0 = {0.f, 0.f, 0.f, 0.f}, v1 = {0.f, 0.f, 0.f, 0.f};
            if (grow < N_NODES) {
                const float* sp = srcbase + (size_t)grow * 128 + kbase + c8 * 8;
                v0 = *(const float4*)sp;
                v1 = *(const float4*)(sp + 4);
            }
            float vv[8] = {v0.x, v0.y, v0.z, v0.w, v1.x, v1.y, v1.z, v1.w};
            bf16x8 hv, lv;
            #pragma unroll
            for (int e = 0; e < 8; ++e) {
                short hb = f2bf(vv[e]);
                hv[e] = hb;
                lv[e] = f2bf(vv[e] - bf2f(hb));
            }
            int a16 = r * 8 + (c8 ^ (r & 7));   // 16B-unit swizzled offset
            ((bf16x8*)Ahi)[a16] = hv;
            ((bf16x8*)Alo)[a16] = lv;
        }
        __syncthreads();

        // ---- compute: 2 MFMA k-steps of 32
        #pragma unroll
        for (int ks = 0; ks < 2; ++ks) {
            bf16x8 ah[2], al[2];
            #pragma unroll
            for (int mi = 0; mi < 2; ++mi) {
                int row = wave * 32 + mi * 16 + rr;
                int kchunk = ks * 4 + kg;
                int a16 = row * 8 + (kchunk ^ (row & 7));
                ah[mi] = ((const bf16x8*)Ahi)[a16];
                al[mi] = ((const bf16x8*)Alo)[a16];
            }
            int kglob = kt * 64 + ks * 32 + kg * 8;
            #pragma unroll
            for (int nj = 0; nj < 4; ++nj) {
                int colg = bn * 64 + nj * 16 + rr;
                bf16x8 bh = *(const bf16x8*)(Wt_hi + (size_t)colg * 256 + kglob);
                bf16x8 bl = *(const bf16x8*)(Wt_lo + (size_t)colg * 256 + kglob);
                #pragma unroll
                for (int mi = 0; mi < 2; ++mi) {
                    acc[mi][nj] = __builtin_amdgcn_mfma_f32_16x16x32_bf16(ah[mi], bh, acc[mi][nj], 0, 0, 0);
                    acc[mi][nj] = __builtin_amdgcn_mfma_f32_16x16x32_bf16(al[mi], bh, acc[mi][nj], 0, 0, 0);
                    acc[mi][nj] = __builtin_amdgcn_mfma_f32_16x16x32_bf16(ah[mi], bl, acc[mi][nj], 0, 0, 0);
                }
            }
        }
        __syncthreads();
    }

    // ---- epilogue: bias (+relu), f32 stores. D: col=lane&15, row=(lane>>4)*4+r
    const int rg = lane >> 4;
    #pragma unroll
    for (int mi = 0; mi < 2; ++mi) {
        #pragma unroll
        for (int nj = 0; nj < 4; ++nj) {
            int colg = bn * 64 + nj * 16 + rr;
            float bv = bias[colg];
            #pragma unroll
            for (int r = 0; r < 4; ++r) {
                int row = row0 + wave * 32 + mi * 16 + rg * 4 + r;
                if (row < N_NODES) {
                    float v = acc[mi][nj][r] + bv;
                    if (RELU) v = fmaxf(v, 0.f);
                    out[(size_t)row * NOUT + colg] = v;
                }
            }
        }
    }
}

// ---------------------------------------------------------------- launch

extern "C" void kernel_launch(void* const* d_in, const int* in_sizes, int n_in,
                              void* d_out, int out_size, void* d_ws, size_t ws_size,
                              hipStream_t stream) {
    const float* x   = (const float*)d_in[0];
    const int*   src = (const int*)d_in[1];
    const int*   dst = (const int*)d_in[2];
    const float* Ws0 = (const float*)d_in[3];
    const float* Wn0 = (const float*)d_in[4];
    const float* b0  = (const float*)d_in[5];
    const float* Ws1 = (const float*)d_in[6];
    const float* Wn1 = (const float*)d_in[7];
    const float* b1  = (const float*)d_in[8];
    const float* Ws2 = (const float*)d_in[9];
    const float* Wn2 = (const float*)d_in[10];
    const float* b2  = (const float*)d_in[11];
    float* out = (float*)d_out;

    char* p = (char*)d_ws;
    auto alloc = [&](size_t bytes) {
        char* r = p;
        p += (bytes + 255) & ~(size_t)255;
        return r;
    };
    int*   cnt      = (int*)alloc((size_t)N_NODES * 4);
    int*   cursor   = (int*)alloc((size_t)N_NODES * 4);
    int*   rowptr   = (int*)alloc((size_t)(N_NODES + 1) * 4);
    int*   col      = (int*)alloc((size_t)N_EDGES * 4);
    float* deginv   = (float*)alloc((size_t)N_NODES * 4);
    int*   partials = (int*)alloc((size_t)NPART * 4);
    int*   offsets  = (int*)alloc((size_t)NPART * 4);
    float* agg      = (float*)alloc((size_t)N_NODES * HIDW * 4);
    float* hA       = (float*)alloc((size_t)N_NODES * HIDW * 4);
    float* hB       = (float*)alloc((size_t)N_NODES * HIDW * 4);
    short* Wt0_hi   = (short*)alloc((size_t)128 * 256 * 2);
    short* Wt0_lo   = (short*)alloc((size_t)128 * 256 * 2);
    short* Wt1_hi   = (short*)alloc((size_t)128 * 256 * 2);
    short* Wt1_lo   = (short*)alloc((size_t)128 * 256 * 2);
    short* Wt2_hi   = (short*)alloc((size_t)64 * 256 * 2);
    short* Wt2_lo   = (short*)alloc((size_t)64 * 256 * 2);

    hipMemsetAsync(cnt, 0, (size_t)N_NODES * 4, stream);
    hipMemsetAsync(cursor, 0, (size_t)N_NODES * 4, stream);

    // CSR build
    count_kernel<<<(N_EDGES + 255) / 256, 256, 0, stream>>>(dst, cnt);
    scan_part <<<NPART, 256, 0, stream>>>(cnt, partials);
    scan_mid  <<<1, 256, 0, stream>>>(partials, offsets);
    scan_final<<<NPART, 256, 0, stream>>>(cnt, offsets, rowptr);
    fill_kernel<<<(N_EDGES + 255) / 256, 256, 0, stream>>>(src, dst, rowptr, cursor, col);
    deginv_kernel<<<(N_NODES + 255) / 256, 256, 0, stream>>>(cnt, deginv);

    // weight prep (transpose + hi/lo split)
    wsplit_kernel<128><<<(128 * 256 + 255) / 256, 256, 0, stream>>>(Ws0, Wn0, Wt0_hi, Wt0_lo);
    wsplit_kernel<128><<<(128 * 256 + 255) / 256, 256, 0, stream>>>(Ws1, Wn1, Wt1_hi, Wt1_lo);
    wsplit_kernel<64> <<<(64 * 256 + 255) / 256, 256, 0, stream>>>(Ws2, Wn2, Wt2_hi, Wt2_lo);

    const int MB = (N_NODES + 127) / 128;   // 391
    dim3 g01(MB, 2), g2(MB, 1);

    // layer 0
    aggregate_kernel<<<N_NODES, 128, 0, stream>>>(x, rowptr, col, deginv, agg);
    combine_mfma<128, true><<<g01, 256, 0, stream>>>(x, agg, Wt0_hi, Wt0_lo, b0, hA);
    // layer 1
    aggregate_kernel<<<N_NODES, 128, 0, stream>>>(hA, rowptr, col, deginv, agg);
    combine_mfma<128, true><<<g01, 256, 0, stream>>>(hA, agg, Wt1_hi, Wt1_lo, b1, hB);
    // layer 2
    aggregate_kernel<<<N_NODES, 128, 0, stream>>>(hB, rowptr, col, deginv, agg);
    combine_mfma<64, false><<<g2, 256, 0, stream>>>(hB, agg, Wt2_hi, Wt2_lo, b2, out);
}